// Round 9
// baseline (321.732 us; speedup 1.0000x reference)
//
#include <hip/hip_runtime.h>
#include <math.h>

#define N4C 32768
#define N3C 65536
#define N2C 131072
#define N1C 262144

typedef _Float16 f16x8 __attribute__((ext_vector_type(8)));
typedef _Float16 f16x4 __attribute__((ext_vector_type(4)));
typedef float f32x4 __attribute__((ext_vector_type(4)));

__device__ __forceinline__ f32x4 mfma16(f16x8 a, f16x8 b, f32x4 c) {
  return __builtin_amdgcn_mfma_f32_16x16x32_f16(a, b, c, 0, 0, 0);
}

// fast celu: expm1(x) ~= __expf(x)-1 (v_exp_f32, abs err ~1e-7)
__device__ __forceinline__ float celuf(float x) {
  return x > 0.f ? x : (__expf(x) - 1.f);
}

// log_sigmoid(x) = min(x,0) - log(1 + exp(-|x|))
__device__ __forceinline__ float logsigf(float x) {
  float e = __expf(-fabsf(x));
  return fminf(x, 0.f) - __logf(1.f + e);
}

// ---------------------------------------------------------------------------
// Prep: zext [N4][72] f16 rows = [feat 0..63][pos4 x,y,z][pad].
// One gather target per l3 edge: feature row carries its own position.
// 16 threads per row: subs 0..7 write f16x8 feat segments, sub 8 writes pos.
// ---------------------------------------------------------------------------
__global__ __launch_bounds__(256) void zprep_kernel(const float* __restrict__ z,
                                                    const float* __restrict__ pos4,
                                                    _Float16* __restrict__ zext) {
  const int r = blockIdx.x * 16 + (threadIdx.x >> 4);
  const int sub = threadIdx.x & 15;
  _Float16* row = zext + (size_t)r * 72;
  if (sub < 8) {
    float4 f0 = *(const float4*)(z + r * 64 + sub * 8);
    float4 f1 = *(const float4*)(z + r * 64 + sub * 8 + 4);
    f16x8 h;
    h[0] = (_Float16)f0.x; h[1] = (_Float16)f0.y;
    h[2] = (_Float16)f0.z; h[3] = (_Float16)f0.w;
    h[4] = (_Float16)f1.x; h[5] = (_Float16)f1.y;
    h[6] = (_Float16)f1.z; h[7] = (_Float16)f1.w;
    *(f16x8*)(row + sub * 8) = h;
  } else if (sub == 8) {
    f16x4 h;
    h[0] = (_Float16)pos4[r * 3 + 0];
    h[1] = (_Float16)pos4[r * 3 + 1];
    h[2] = (_Float16)pos4[r * 3 + 2];
    h[3] = (_Float16)0.f;
    *(f16x4*)(row + 64) = h;
  }
}

// ---------------------------------------------------------------------------
// Level 3: PointConv (64 -> 64 -> 32), f16 MFMA, wave per point (16 edges = M).
// Round-8 skeleton. Single gather target per edge (pos4 embedded in zext);
// rel computed in f16. Output x3ext rows embed pos3 for l2.
// Pad halfs are 0xAA poison = finite f16; they hit zero-masked B cols only.
// ---------------------------------------------------------------------------
__global__ __launch_bounds__(256) void l3_kernel(
    const _Float16* __restrict__ zext, const float* __restrict__ pos3,
    const int* __restrict__ src3,
    const float* __restrict__ w1a, const float* __restrict__ b1a,
    const float* __restrict__ w1b, const float* __restrict__ b1b,
    _Float16* __restrict__ x3ext) {
  __shared__ _Float16 hbuf[4][16 * 80];  // 160 B rows, 16B-aligned reads
  const int lane = threadIdx.x & 63;
  const int wid = threadIdx.x >> 6;
  const int col = lane & 15;   // MFMA n / A row m (edge)
  const int quad = lane >> 4;  // k-subchunk selector
  _Float16* hw = hbuf[wid];

  // B frags layer a: B[k][n], k = c*32 + quad*8 + j (K=67 pad 96), n = t*16+col
  f16x8 Ba[3][4];
#pragma unroll
  for (int c = 0; c < 3; ++c)
#pragma unroll
    for (int t = 0; t < 4; ++t)
#pragma unroll
      for (int j = 0; j < 8; ++j) {
        int k = c * 32 + quad * 8 + j;
        Ba[c][t][j] = (k < 67) ? (_Float16)w1a[k * 64 + t * 16 + col] : (_Float16)0.f;
      }
  f16x8 Bb[2][2];
#pragma unroll
  for (int c = 0; c < 2; ++c)
#pragma unroll
    for (int t = 0; t < 2; ++t)
#pragma unroll
      for (int j = 0; j < 8; ++j) {
        int k = c * 32 + quad * 8 + j;
        Bb[c][t][j] = (_Float16)w1b[k * 32 + t * 16 + col];
      }
  const float biasA0 = b1a[col], biasA1 = b1a[16 + col];
  const float biasA2 = b1a[32 + col], biasA3 = b1a[48 + col];
  const float biasB0 = b1b[col], biasB1 = b1b[16 + col];

  const int gwave = blockIdx.x * 4 + wid;
  const int nw = gridDim.x * 4;

  for (int p = gwave; p < N3C; p += nw) {
    const int s = src3[p * 16 + col];
    const int up = __builtin_amdgcn_readfirstlane(p);  // wave-uniform -> s_load
    const float po0 = pos3[up * 3 + 0];
    const float po1 = pos3[up * 3 + 1];
    const float po2 = pos3[up * 3 + 2];

    const _Float16* zr = zext + (size_t)s * 72;
    f16x8 A0 = *(const f16x8*)(zr + quad * 8);        // k 0..31
    f16x8 A1 = *(const f16x8*)(zr + 32 + quad * 8);   // k 32..63
    f16x8 A2 = {};
    if (quad == 0) {                                  // k 64..66 = rel (f16)
      f16x8 t = *(const f16x8*)(zr + 64);
      t[0] = t[0] - (_Float16)po0;
      t[1] = t[1] - (_Float16)po1;
      t[2] = t[2] - (_Float16)po2;
      A2 = t;  // j>=3: pad garbage * zero weights = 0
    }

    f32x4 d[4];
#pragma unroll
    for (int t = 0; t < 4; ++t) {
      f32x4 acc = {0.f, 0.f, 0.f, 0.f};
      acc = mfma16(A0, Ba[0][t], acc);
      acc = mfma16(A1, Ba[1][t], acc);
      acc = mfma16(A2, Ba[2][t], acc);
      d[t] = acc;
    }
    // C layout: row = quad*4 + r, col = n. celu -> f16 LDS [16][80].
#pragma unroll
    for (int r = 0; r < 4; ++r) {
      _Float16* bp = hw + (quad * 4 + r) * 80 + col;
      bp[0]  = (_Float16)celuf(d[0][r] + biasA0);
      bp[16] = (_Float16)celuf(d[1][r] + biasA1);
      bp[32] = (_Float16)celuf(d[2][r] + biasA2);
      bp[48] = (_Float16)celuf(d[3][r] + biasA3);
    }
    // same-wave LDS, in-order: no barrier. A'[m=col][k=c*32+quad*8+j]
    f16x8 P0 = *(const f16x8*)(hw + col * 80 + quad * 8);
    f16x8 P1 = *(const f16x8*)(hw + col * 80 + 32 + quad * 8);
    f32x4 e[2];
#pragma unroll
    for (int t = 0; t < 2; ++t) {
      f32x4 acc = {0.f, 0.f, 0.f, 0.f};
      acc = mfma16(P0, Bb[0][t], acc);
      acc = mfma16(P1, Bb[1][t], acc);
      e[t] = acc;
    }
    float m0 = fmaxf(fmaxf(e[0][0], e[0][1]), fmaxf(e[0][2], e[0][3]));
    float m1 = fmaxf(fmaxf(e[1][0], e[1][1]), fmaxf(e[1][2], e[1][3]));
    m0 = fmaxf(m0, __shfl_xor(m0, 16, 64));
    m0 = fmaxf(m0, __shfl_xor(m0, 32, 64));
    m1 = fmaxf(m1, __shfl_xor(m1, 16, 64));
    m1 = fmaxf(m1, __shfl_xor(m1, 32, 64));
    _Float16* row = x3ext + (size_t)p * 40;
    if (lane < 16) {
      row[col]      = (_Float16)celuf(m0 + biasB0);  // max(x)+b == max(x+b)
      row[16 + col] = (_Float16)celuf(m1 + biasB1);
    }
    if (lane == 0) {  // embed pos3[p] for l2's rel
      f16x4 hp;
      hp[0] = (_Float16)po0; hp[1] = (_Float16)po1;
      hp[2] = (_Float16)po2; hp[3] = (_Float16)0.f;
      *(f16x4*)(row + 32) = hp;
    }
  }
}

// ---------------------------------------------------------------------------
// Level 2: PointConv (32 -> 16 -> 16), f16 MFMA wave-per-point.
// Single gather target per edge (pos3 embedded in x3ext rows of 40 halfs).
// Output x2ext rows (32 halfs = one 64-B line) embed pos2 for l1.
// ---------------------------------------------------------------------------
__global__ __launch_bounds__(256) void l2_kernel(
    const _Float16* __restrict__ x3ext, const float* __restrict__ pos2,
    const int* __restrict__ src2,
    const float* __restrict__ w2a, const float* __restrict__ b2a,
    const float* __restrict__ w2b, const float* __restrict__ b2b,
    _Float16* __restrict__ x2ext) {
  __shared__ _Float16 hbuf[4][16 * 24];  // 48 B rows, 16B-aligned reads
  const int lane = threadIdx.x & 63;
  const int wid = threadIdx.x >> 6;
  const int col = lane & 15;
  const int quad = lane >> 4;
  _Float16* hw = hbuf[wid];

  f16x8 Ba0, Ba1, Bb;
#pragma unroll
  for (int j = 0; j < 8; ++j) {
    int k = quad * 8 + j;
    Ba0[j] = (_Float16)w2a[k * 16 + col];                       // k 0..31
    Ba1[j] = (k + 32 < 35) ? (_Float16)w2a[(k + 32) * 16 + col] // k 32..34
                           : (_Float16)0.f;
    Bb[j] = (k < 16) ? (_Float16)w2b[k * 16 + col] : (_Float16)0.f;
  }
  const float biasA = b2a[col];
  const float biasB = b2b[col];

  const int gwave = blockIdx.x * 4 + wid;
  const int nw = gridDim.x * 4;

  f16x8 P = {};  // quads 0,1 fully rewritten per point

  for (int p = gwave; p < N2C; p += nw) {
    const int s = src2[p * 16 + col];
    const int up = __builtin_amdgcn_readfirstlane(p);
    const float po0 = pos2[up * 3 + 0];
    const float po1 = pos2[up * 3 + 1];
    const float po2 = pos2[up * 3 + 2];

    const _Float16* xr = x3ext + (size_t)s * 40;
    f16x8 A0 = *(const f16x8*)(xr + quad * 8);  // k 0..31 = feat
    f16x8 A1 = {};
    if (quad == 0) {                            // k 32..34 = rel (f16)
      f16x8 t = *(const f16x8*)(xr + 32);
      t[0] = t[0] - (_Float16)po0;
      t[1] = t[1] - (_Float16)po1;
      t[2] = t[2] - (_Float16)po2;
      A1 = t;  // j>=3: pad garbage * zero weights = 0
    }

    f32x4 d = {0.f, 0.f, 0.f, 0.f};
    d = mfma16(A0, Ba0, d);
    d = mfma16(A1, Ba1, d);
#pragma unroll
    for (int r = 0; r < 4; ++r)
      hw[(quad * 4 + r) * 24 + col] = (_Float16)celuf(d[r] + biasA);

    if (quad < 2) {  // k 0..15 valid: one b128 f16 read, no cvt
      P = *(const f16x8*)(hw + col * 24 + quad * 8);
    }
    f32x4 e = {0.f, 0.f, 0.f, 0.f};
    e = mfma16(P, Bb, e);

    float m0 = fmaxf(fmaxf(e[0], e[1]), fmaxf(e[2], e[3]));
    m0 = fmaxf(m0, __shfl_xor(m0, 16, 64));
    m0 = fmaxf(m0, __shfl_xor(m0, 32, 64));
    _Float16* row = x2ext + (size_t)p * 32;
    if (lane < 16) row[col] = (_Float16)celuf(m0 + biasB);
    if (lane == 0) {  // embed pos2[p] for l1's rel
      f16x4 hp;
      hp[0] = (_Float16)po0; hp[1] = (_Float16)po1;
      hp[2] = (_Float16)po2; hp[3] = (_Float16)0.f;
      *(f16x4*)(row + 16) = hp;
    }
  }
}

// ---------------------------------------------------------------------------
// Level 1: PointConv (16 -> 8 -> 8) + final linear + log_sigmoid.
// Single gather target per edge: x2ext row (one 64-B line) = feat + pos2.
// ---------------------------------------------------------------------------
__global__ __launch_bounds__(256) void l1_kernel(
    const _Float16* __restrict__ x2ext, const float* __restrict__ pos1,
    const int* __restrict__ src1,
    const float* __restrict__ w3a, const float* __restrict__ b3a,
    const float* __restrict__ w3b, const float* __restrict__ b3b,
    const float* __restrict__ wlin, const float* __restrict__ blin,
    float* __restrict__ out) {
  __shared__ _Float16 hbuf[4][16 * 8];  // 16 B rows
  const int lane = threadIdx.x & 63;
  const int wid = threadIdx.x >> 6;
  const int col = lane & 15;
  const int quad = lane >> 4;
  _Float16* hw = hbuf[wid];

  f16x8 Ba, Bb;
#pragma unroll
  for (int j = 0; j < 8; ++j) {
    int k = quad * 8 + j;
    Ba[j] = (k < 19 && col < 8) ? (_Float16)w3a[k * 8 + col] : (_Float16)0.f;
    Bb[j] = (k < 8 && col < 8) ? (_Float16)w3b[k * 8 + col] : (_Float16)0.f;
  }
  const float biasA = (col < 8) ? b3a[col] : 0.f;
  const float biasB = (col < 8) ? b3b[col] : 0.f;
  const float wl = (col < 8) ? wlin[col] : 0.f;
  const float bl = blin[0];

  const int gwave = blockIdx.x * 4 + wid;
  const int nw = gridDim.x * 4;

  f16x8 P = {};  // quad0 fully rewritten per point

  for (int p = gwave; p < N1C; p += nw) {
    const int s = src1[p * 16 + col];
    const int up = __builtin_amdgcn_readfirstlane(p);
    const float po0 = pos1[up * 3 + 0];
    const float po1 = pos1[up * 3 + 1];
    const float po2 = pos1[up * 3 + 2];

    // A[m=col=edge][k=quad*8+j]: quads 0,1 = feat; quad 2 = rel (embedded pos2)
    const _Float16* xr = x2ext + (size_t)s * 32;
    f16x8 A = {};
    if (quad < 2) {
      A = *(const f16x8*)(xr + quad * 8);
    } else if (quad == 2) {
      f16x8 t = *(const f16x8*)(xr + 16);  // halfs 16..18 = pos2, 19.. pad
      t[0] = t[0] - (_Float16)po0;
      t[1] = t[1] - (_Float16)po1;
      t[2] = t[2] - (_Float16)po2;
      A = t;  // k>=19: garbage * zero weights = 0
    }
    f32x4 d = {0.f, 0.f, 0.f, 0.f};
    d = mfma16(A, Ba, d);

    if (col < 8) {
#pragma unroll
      for (int r = 0; r < 4; ++r)
        hw[(quad * 4 + r) * 8 + col] = (_Float16)celuf(d[r] + biasA);
    }
    if (quad == 0) {  // k = 0..7 valid: whole f16 row in one b128 read
      P = *(const f16x8*)(hw + col * 8);
    }
    f32x4 e = {0.f, 0.f, 0.f, 0.f};
    e = mfma16(P, Bb, e);

    float m0 = fmaxf(fmaxf(e[0], e[1]), fmaxf(e[2], e[3]));
    m0 = fmaxf(m0, __shfl_xor(m0, 16, 64));
    m0 = fmaxf(m0, __shfl_xor(m0, 32, 64));
    // lane0 needs sum over cols 0..7 (cols 8..15 contribute 0): 3 shuffles
    float t = (col < 8) ? celuf(m0 + biasB) * wl : 0.f;
    t += __shfl_xor(t, 1, 64);
    t += __shfl_xor(t, 2, 64);
    t += __shfl_xor(t, 4, 64);
    if (lane == 0) out[p] = logsigf(t + bl);
  }
}

extern "C" void kernel_launch(void* const* d_in, const int* in_sizes, int n_in,
                              void* d_out, int out_size, void* d_ws, size_t ws_size,
                              hipStream_t stream) {
  const float* z_mask = (const float*)d_in[0];
  const float* pos4 = (const float*)d_in[1];
  const float* pos3 = (const float*)d_in[2];
  const float* pos2 = (const float*)d_in[3];
  const float* pos1 = (const float*)d_in[4];
  const float* w1a = (const float*)d_in[9];
  const float* b1a = (const float*)d_in[10];
  const float* w1b = (const float*)d_in[11];
  const float* b1b = (const float*)d_in[12];
  const float* w2a = (const float*)d_in[13];
  const float* b2a = (const float*)d_in[14];
  const float* w2b = (const float*)d_in[15];
  const float* b2b = (const float*)d_in[16];
  const float* w3a = (const float*)d_in[17];
  const float* b3a = (const float*)d_in[18];
  const float* w3b = (const float*)d_in[19];
  const float* b3b = (const float*)d_in[20];
  const float* wlin = (const float*)d_in[21];
  const float* blin = (const float*)d_in[22];
  const int* src3 = (const int*)d_in[23];
  const int* src2 = (const int*)d_in[25];
  const int* src1 = (const int*)d_in[27];

  // ws layout: [x3ext 5.24 MB][regionB 8.39 MB]  (<= 16 MB)
  // regionB: zext [N4][72] (live prep..l3) then x2ext [N2][32] (live l2..l1).
  _Float16* x3ext = (_Float16*)d_ws;                           // [N3][40] f16
  char* regionB = (char*)d_ws + (size_t)N3C * 40 * 2;
  _Float16* zext = (_Float16*)regionB;                         // [N4][72] f16
  _Float16* x2ext = (_Float16*)regionB;                        // [N2][32] f16
  float* out = (float*)d_out;

  zprep_kernel<<<N4C / 16, 256, 0, stream>>>(z_mask, pos4, zext);
  l3_kernel<<<2048, 256, 0, stream>>>(zext, pos3, src3, w1a, b1a, w1b, b1b, x3ext);
  l2_kernel<<<8192, 256, 0, stream>>>(x3ext, pos2, src2, w2a, b2a, w2b, b2b, x2ext);
  l1_kernel<<<8192, 256, 0, stream>>>(x2ext, pos1, src1, w3a, b3a, w3b, b3b,
                                      wlin, blin, out);
}